// Round 4
// baseline (325.437 us; speedup 1.0000x reference)
//
#include <hip/hip_runtime.h>

typedef __bf16 bf16_t;
typedef __bf16 bf16x8 __attribute__((ext_vector_type(8)));
typedef float f32x4 __attribute__((ext_vector_type(4)));
typedef float f32x16 __attribute__((ext_vector_type(16)));

// Problem constants: B=4, S=2048, E=1024, H=16, D=64

__device__ __forceinline__ void async_copy16(const void* g, void* l) {
  __builtin_amdgcn_global_load_lds(
      (const __attribute__((address_space(1))) void*)g,
      (__attribute__((address_space(3))) void*)l, 16, 0, 0);
}

__device__ __forceinline__ unsigned pk_bf16(float lo, float hi) {
  unsigned r;
  asm("v_cvt_pk_bf16_f32 %0, %1, %2" : "=v"(r) : "v"(lo), "v"(hi));
  return r;
}

// ---------------------------------------------------------------------------
// Fused fp32 -> bf16 convert for all 7 tensors (outputs contiguous in ws).
// ---------------------------------------------------------------------------
__global__ void cvt_all_kernel(const float* __restrict__ q, const float* __restrict__ k,
                               const float* __restrict__ v, const float* __restrict__ wk,
                               const float* __restrict__ wv, const float* __restrict__ wq,
                               const float* __restrict__ wo, uint2* __restrict__ out) {
  constexpr int QX = 2097152, QW = 262144;
  int g = blockIdx.x * 256 + threadIdx.x;
  const float* in; int off;
  if (g < QX)               { in = q;  off = 0; }
  else if (g < 2 * QX)      { in = k;  off = QX; }
  else if (g < 3 * QX)      { in = v;  off = 2 * QX; }
  else if (g < 3 * QX + QW)     { in = wk; off = 3 * QX; }
  else if (g < 3 * QX + 2 * QW) { in = wv; off = 3 * QX + QW; }
  else if (g < 3 * QX + 3 * QW) { in = wq; off = 3 * QX + 2 * QW; }
  else                          { in = wo; off = 3 * QX + 3 * QW; }
  float4 val = ((const float4*)in)[g - off];
  union { bf16_t h[4]; uint2 u; } cv;
  cv.h[0] = (bf16_t)val.x; cv.h[1] = (bf16_t)val.y;
  cv.h[2] = (bf16_t)val.z; cv.h[3] = (bf16_t)val.w;
  out[g] = cv.u;
}

// ---------------------------------------------------------------------------
// Fused Q/K/V projection GEMM. Grid (64, 24), 256 threads.
//  by>>3 == 0: Qp[B,H,S,D] = (qb @ Wq^T) * qscale
//  by>>3 == 1: Kp[B,H,S,D] =  kb @ Wk^T
//  by>>3 == 2: Vt[B,H,D,S] = (vb @ Wv^T)^T  (swapped operands)
// 128x128 tile, BK=32. LDS chunk placement XOR-swizzled (inverted at the
// global source; dest stays base+lane*16): fragment ds_read_b128 -> 2-way.
// ---------------------------------------------------------------------------
__global__ __launch_bounds__(256) void qkv_kernel(
    const bf16_t* __restrict__ qb, const bf16_t* __restrict__ kb, const bf16_t* __restrict__ vb,
    const bf16_t* __restrict__ wqb, const bf16_t* __restrict__ wkb, const bf16_t* __restrict__ wvb,
    bf16_t* __restrict__ Qp, bf16_t* __restrict__ Kp, bf16_t* __restrict__ Vt, float qscale)
{
  constexpr int K = 1024;
  __shared__ __align__(16) bf16_t As[128 * 32];
  __shared__ __align__(16) bf16_t Bs[128 * 32];
  const int tid  = threadIdx.x;
  const int lane = tid & 63;
  const int wid  = tid >> 6;
  const int quad = lane >> 4;
  const int l16  = lane & 15;
  const int bx = blockIdx.x, by = blockIdx.y;
  const int sel = by >> 3, sub = by & 7;
  const bf16_t *X, *W; bf16_t* Y; float scale = 1.0f;
  int m0, n0;
  if (sel == 0)      { X = qb;  W = wqb; Y = Qp; m0 = bx * 128; n0 = sub * 128; scale = qscale; }
  else if (sel == 1) { X = kb;  W = wkb; Y = Kp; m0 = bx * 128; n0 = sub * 128; }
  else               { X = wvb; W = vb;  Y = Vt; m0 = sub * 128; n0 = bx * 128; }
  const int wm = (wid >> 1) * 64;
  const int wn = (wid & 1) * 64;
  const int swz = quad ^ ((l16 >> 1) & 3);     // per-lane fragment swizzle

  f32x4 acc[4][4] = {};

  for (int k0 = 0; k0 < K; k0 += 32) {
#pragma unroll
    for (int p = 0; p < 2; ++p) {
      int c = tid + p * 256;                   // dest chunk (linear)
      int row = c >> 2;
      int seg = ((c & 3) ^ ((c >> 3) & 3)) * 8;  // swizzle-inverted source seg
      async_copy16(&X[(size_t)(m0 + row) * K + k0 + seg], (char*)As + (p * 256 + wid * 64) * 16);
      async_copy16(&W[(size_t)(n0 + row) * K + k0 + seg], (char*)Bs + (p * 256 + wid * 64) * 16);
    }
    __syncthreads();
    bf16x8 af[4], bfr[4];
#pragma unroll
    for (int i = 0; i < 4; ++i)
      af[i] = *(const bf16x8*)((const char*)As + ((wm + i * 16 + l16) * 4 + swz) * 16);
#pragma unroll
    for (int j = 0; j < 4; ++j)
      bfr[j] = *(const bf16x8*)((const char*)Bs + ((wn + j * 16 + l16) * 4 + swz) * 16);
#pragma unroll
    for (int i = 0; i < 4; ++i)
#pragma unroll
      for (int j = 0; j < 4; ++j)
        acc[i][j] = __builtin_amdgcn_mfma_f32_16x16x32_bf16(af[i], bfr[j], acc[i][j], 0, 0, 0);
    __syncthreads();
  }

#pragma unroll
  for (int i = 0; i < 4; ++i)
#pragma unroll
    for (int j = 0; j < 4; ++j)
#pragma unroll
      for (int r = 0; r < 4; ++r) {
        int row = m0 + wm + i * 16 + quad * 4 + r;
        int col = n0 + wn + j * 16 + l16;
        float val = acc[i][j][r] * scale;
        if (sel < 2) {                               // [B,H,S,D]
          int b = row >> 11, s = row & 2047;
          int h = col >> 6,  d = col & 63;
          Y[(((size_t)(b * 16 + h) << 11) + s) * 64 + d] = (bf16_t)val;
        } else {                                     // [B,H,D,S]
          int h = row >> 6,  d = row & 63;
          int b = col >> 11, s = col & 2047;
          Y[(((size_t)((b * 16 + h) * 64 + d)) << 11) + s] = (bf16_t)val;
        }
      }
}

// ---------------------------------------------------------------------------
// Output projection: out = Ob @ Wo^T, fp32 [M,N] row-major. Same swizzle.
// ---------------------------------------------------------------------------
__global__ __launch_bounds__(256) void out_gemm_kernel(
    const bf16_t* __restrict__ X, const bf16_t* __restrict__ W,
    float* __restrict__ Y, int M, int N, int K)
{
  __shared__ __align__(16) bf16_t As[128 * 32];
  __shared__ __align__(16) bf16_t Bs[128 * 32];
  const int tid  = threadIdx.x;
  const int lane = tid & 63;
  const int wid  = tid >> 6;
  const int quad = lane >> 4;
  const int l16  = lane & 15;
  const int m0 = blockIdx.x * 128;
  const int n0 = blockIdx.y * 128;
  const int wm = (wid >> 1) * 64;
  const int wn = (wid & 1) * 64;
  const int swz = quad ^ ((l16 >> 1) & 3);

  f32x4 acc[4][4] = {};

  for (int k0 = 0; k0 < K; k0 += 32) {
#pragma unroll
    for (int p = 0; p < 2; ++p) {
      int c = tid + p * 256;
      int row = c >> 2;
      int seg = ((c & 3) ^ ((c >> 3) & 3)) * 8;
      async_copy16(&X[(size_t)(m0 + row) * K + k0 + seg], (char*)As + (p * 256 + wid * 64) * 16);
      async_copy16(&W[(size_t)(n0 + row) * K + k0 + seg], (char*)Bs + (p * 256 + wid * 64) * 16);
    }
    __syncthreads();
    bf16x8 af[4], bfr[4];
#pragma unroll
    for (int i = 0; i < 4; ++i)
      af[i] = *(const bf16x8*)((const char*)As + ((wm + i * 16 + l16) * 4 + swz) * 16);
#pragma unroll
    for (int j = 0; j < 4; ++j)
      bfr[j] = *(const bf16x8*)((const char*)Bs + ((wn + j * 16 + l16) * 4 + swz) * 16);
#pragma unroll
    for (int i = 0; i < 4; ++i)
#pragma unroll
      for (int j = 0; j < 4; ++j)
        acc[i][j] = __builtin_amdgcn_mfma_f32_16x16x32_bf16(af[i], bfr[j], acc[i][j], 0, 0, 0);
    __syncthreads();
  }

#pragma unroll
  for (int i = 0; i < 4; ++i)
#pragma unroll
    for (int j = 0; j < 4; ++j)
#pragma unroll
      for (int r = 0; r < 4; ++r) {
        int row = m0 + wm + i * 16 + quad * 4 + r;
        int col = n0 + wn + j * 16 + l16;
        Y[(size_t)row * N + col] = acc[i][j][r];
      }
}

// ---------------------------------------------------------------------------
// Causal flash attention, v3b: swapped QK^T + in-register softmax + split-k
// load balancing, DETERMINISTIC combine (no atomics, no memset).
// m=0 exp2 softmax => partial O / rowsum over disjoint k-ranges are purely
// additive. Heavy q-tiles (15..8, rows 1024..2047) are computed by 2 blocks
// (k-halves) writing to separate fp32 partial buffers with plain stores;
// attn_norm_kernel sums + normalizes. Light tiles (7..0) store bf16 direct.
// Grid (24, 64): bx<16 -> half-chunks (9..16 steps); bx>=16 -> whole tiles
// (2..16 steps). Max steps/block 32 -> 16; 1536 blocks over 1024 residency
// slots -> scheduler backfill through the tail.
// ---------------------------------------------------------------------------
__global__ __launch_bounds__(256, 3) void attn_kernel(
    const bf16_t* __restrict__ Qp, const bf16_t* __restrict__ Kp,
    const bf16_t* __restrict__ Vt, bf16_t* __restrict__ O,
    float* __restrict__ Oacc, float* __restrict__ Racc)
{
  constexpr int S = 2048, D = 64, E = 1024;
  constexpr int BQ = 128, BK = 64;
  __shared__ __align__(16) bf16_t Ks[2][8 * 64 * 8];   // [buf][panel=d>>3][krow][8]
  __shared__ __align__(16) bf16_t Vs[2][8 * 64 * 8];   // [buf][panel=k>>3][drow][8]
  __shared__ float rsbuf[128];

  const int tid = threadIdx.x, lane = tid & 63, wid = tid >> 6;
  const int l31 = lane & 31, hi = lane >> 5;
  const int bh = blockIdx.y;
  const int b = bh >> 4, h = bh & 15;

  // ---- block -> (q-tile, k-chunk) mapping (block-uniform scalar) ---------
  const int bx = blockIdx.x;                 // 0..23, heavy chunks first
  int qt, s0, s1, half; bool direct;
  if (bx < 16) {
    qt = 15 - (bx >> 1);                     // tiles 15..8, two halves each
    const int nks = 2 * qt + 2;
    half = bx & 1;
    s0 = half ? nks / 2 : 0;
    s1 = half ? nks : nks / 2;
    direct = false;
  } else {
    qt = 23 - bx;                            // tiles 7..0, whole
    s0 = 0; s1 = 2 * qt + 2; half = 0;
    direct = true;
  }

  const int q0 = qt * BQ;
  const size_t base  = (size_t)bh * S * D;
  const size_t baseV = (size_t)bh * D * S;
  const int qmin = q0 + wid * 32;
  const int qmax = qmin + 31;

  // Q fragments (B-operand): lane holds Q[qmin+l31][ks*16 + hi*8 + j]
  bf16x8 qf[4];
#pragma unroll
  for (int ks = 0; ks < 4; ++ks)
    qf[ks] = *(const bf16x8*)&Qp[base + (size_t)(qmin + l31) * D + ks * 16 + hi * 8];

  // stage k-tile s0 into buffer s0&1
  {
    const int kb0 = s0 * BK;
#pragma unroll
    for (int is = 0; is < 2; ++is) {
      const int c = is * 256 + tid;
      const int p = c >> 6, row = c & 63;
      async_copy16(&Kp[base + (size_t)(kb0 + row) * D + p * 8],
                   (char*)Ks[s0 & 1] + (is * 256 + wid * 64) * 16);
      async_copy16(&Vt[baseV + (size_t)row * S + kb0 + p * 8],
                   (char*)Vs[s0 & 1] + (is * 256 + wid * 64) * 16);
    }
  }
  __syncthreads();

  const f32x16 z16 = {};
  f32x16 oa0 = {}, oa1 = {};
  float rs = 0.0f;

  for (int kt = s0; kt < s1; ++kt) {
    const int cur = kt & 1;
    const int k0 = kt * BK;
    // prefetch next K/V tile into the other buffer (overlaps compute;
    // __syncthreads at loop bottom drains vmcnt)
    if (kt + 1 < s1) {
      const int k0n = k0 + BK;
#pragma unroll
      for (int is = 0; is < 2; ++is) {
        const int c = is * 256 + tid;
        const int p = c >> 6, row = c & 63;
        async_copy16(&Kp[base + (size_t)(k0n + row) * D + p * 8],
                     (char*)Ks[cur ^ 1] + (is * 256 + wid * 64) * 16);
        async_copy16(&Vt[baseV + (size_t)row * S + k0n + p * 8],
                     (char*)Vs[cur ^ 1] + (is * 256 + wid * 64) * 16);
      }
    }
    if (k0 <= qmax) {                      // wave-uniform causal skip
      const bf16_t* ksb = Ks[cur];
      const bf16_t* vsb = Vs[cur];
      // ---- S^T = K Q^T (swapped): sc{0,1} = k-blocks 0..31 / 32..63 ------
      f32x16 sc0, sc1;
      {
        const bf16x8 kf0 = *(const bf16x8*)&ksb[(hi * 64 + l31) * 8];
        const bf16x8 kf1 = *(const bf16x8*)&ksb[(hi * 64 + 32 + l31) * 8];
        sc0 = __builtin_amdgcn_mfma_f32_32x32x16_bf16(kf0, qf[0], z16, 0, 0, 0);
        sc1 = __builtin_amdgcn_mfma_f32_32x32x16_bf16(kf1, qf[0], z16, 0, 0, 0);
      }
#pragma unroll
      for (int ks = 1; ks < 4; ++ks) {
        const bf16x8 kf0 = *(const bf16x8*)&ksb[((ks * 2 + hi) * 64 + l31) * 8];
        const bf16x8 kf1 = *(const bf16x8*)&ksb[((ks * 2 + hi) * 64 + 32 + l31) * 8];
        sc0 = __builtin_amdgcn_mfma_f32_32x32x16_bf16(kf0, qf[ks], sc0, 0, 0, 0);
        sc1 = __builtin_amdgcn_mfma_f32_32x32x16_bf16(kf1, qf[ks], sc1, 0, 0, 0);
      }
      // ---- causal mask (value compare, compile-time reg indices) ---------
      if (k0 + 63 > qmin) {
        const int qg = qmin + l31;
#pragma unroll
        for (int r = 0; r < 16; ++r) {
          const int kg = k0 + (r & 3) + 8 * (r >> 2) + 4 * hi;
          if (kg > qg)      sc0[r] = -1e30f;
          if (kg + 32 > qg) sc1[r] = -1e30f;
        }
      }
      // ---- P = exp2(S) in place ------------------------------------------
#pragma unroll
      for (int r = 0; r < 16; ++r) {
        sc0[r] = __builtin_amdgcn_exp2f(sc0[r]);
        sc1[r] = __builtin_amdgcn_exp2f(sc1[r]);
      }
      // ---- rowsum (this lane's k-half of column q = qmin+l31) ------------
      {
        float s0a = 0.f, s1a = 0.f, s2a = 0.f, s3a = 0.f;
#pragma unroll
        for (int r = 0; r < 16; r += 4) {
          s0a += sc0[r]     + sc1[r];
          s1a += sc0[r + 1] + sc1[r + 1];
          s2a += sc0[r + 2] + sc1[r + 2];
          s3a += sc0[r + 3] + sc1[r + 3];
        }
        rs += (s0a + s1a) + (s2a + s3a);
      }
      // ---- pack P -> PV A-fragments (cvt_pk + permlane32_swap) -----------
      // swap(dst=low-k, src=high-k): dst -> {dst.lo, src.lo} = frag word0,
      //                              src -> {dst.hi, src.hi} = frag word2.
      unsigned pw[16];
      {
        unsigned a0 = pk_bf16(sc0[0], sc0[1]),   a1 = pk_bf16(sc0[2], sc0[3]);
        unsigned b0 = pk_bf16(sc0[4], sc0[5]),   b1 = pk_bf16(sc0[6], sc0[7]);
        unsigned c0 = pk_bf16(sc0[8], sc0[9]),   c1 = pk_bf16(sc0[10], sc0[11]);
        unsigned d0 = pk_bf16(sc0[12], sc0[13]), d1 = pk_bf16(sc0[14], sc0[15]);
        asm("v_permlane32_swap_b32 %0, %1" : "+v"(a0), "+v"(b0));
        asm("v_permlane32_swap_b32 %0, %1" : "+v"(a1), "+v"(b1));
        asm("v_permlane32_swap_b32 %0, %1" : "+v"(c0), "+v"(d0));
        asm("v_permlane32_swap_b32 %0, %1" : "+v"(c1), "+v"(d1));
        pw[0] = a0; pw[1] = a1; pw[2] = b0; pw[3] = b1;
        pw[4] = c0; pw[5] = c1; pw[6] = d0; pw[7] = d1;
      }
      {
        unsigned a0 = pk_bf16(sc1[0], sc1[1]),   a1 = pk_bf16(sc1[2], sc1[3]);
        unsigned b0 = pk_bf16(sc1[4], sc1[5]),   b1 = pk_bf16(sc1[6], sc1[7]);
        unsigned c0 = pk_bf16(sc1[8], sc1[9]),   c1 = pk_bf16(sc1[10], sc1[11]);
        unsigned d0 = pk_bf16(sc1[12], sc1[13]), d1 = pk_bf16(sc1[14], sc1[15]);
        asm("v_permlane32_swap_b32 %0, %1" : "+v"(a0), "+v"(b0));
        asm("v_permlane32_swap_b32 %0, %1" : "+v"(a1), "+v"(b1));
        asm("v_permlane32_swap_b32 %0, %1" : "+v"(c0), "+v"(d0));
        asm("v_permlane32_swap_b32 %0, %1" : "+v"(c1), "+v"(d1));
        pw[8]  = a0; pw[9]  = a1; pw[10] = b0; pw[11] = b1;
        pw[12] = c0; pw[13] = c1; pw[14] = d0; pw[15] = d1;
      }
      // ---- O += P V --------------------------------------------------------
      union U8 { unsigned u[4]; bf16x8 v; };
#pragma unroll
      for (int kb = 0; kb < 2; ++kb)
#pragma unroll
        for (int ks2 = 0; ks2 < 2; ++ks2) {
          U8 pu;
          pu.u[0] = pw[kb * 8 + ks2 * 4 + 0];
          pu.u[1] = pw[kb * 8 + ks2 * 4 + 1];
          pu.u[2] = pw[kb * 8 + ks2 * 4 + 2];
          pu.u[3] = pw[kb * 8 + ks2 * 4 + 3];
          const int pnl = kb * 4 + ks2 * 2 + hi;
          const bf16x8 vf0 = *(const bf16x8*)&vsb[(pnl * 64 + l31) * 8];
          const bf16x8 vf1 = *(const bf16x8*)&vsb[(pnl * 64 + 32 + l31) * 8];
          oa0 = __builtin_amdgcn_mfma_f32_32x32x16_bf16(pu.v, vf0, oa0, 0, 0, 0);
          oa1 = __builtin_amdgcn_mfma_f32_32x32x16_bf16(pu.v, vf1, oa1, 0, 0, 0);
        }
    }
    __syncthreads();                       // drains stage vmcnt + LDS reads
  }

  // ---- epilogue ----------------------------------------------------------
  const float full = rs + __shfl(rs, lane ^ 32);
  if (direct) {
    // combine k-halves of rowsum via LDS broadcast, divide, store bf16
    if (lane < 32) rsbuf[wid * 32 + l31] = full;
    __syncthreads();
#pragma unroll
    for (int r = 0; r < 16; ++r) {
      const int crow = (r & 3) + 8 * (r >> 2) + 4 * hi;
      const float inv = __builtin_amdgcn_rcpf(rsbuf[wid * 32 + crow]);
      const int row = q0 + wid * 32 + crow;
      const size_t rowoff = ((size_t)(b * S + row)) * E + h * D;
      O[rowoff + l31]      = (bf16_t)(oa0[r] * inv);
      O[rowoff + 32 + l31] = (bf16_t)(oa1[r] * inv);
    }
  } else {
    // plain-store partials (rows 1024..2047), buffer selected by k-half
    float* Oh = Oacc + (size_t)half * (64 * 1024 * 64);
    float* Rh = Racc + (size_t)half * (64 * 1024);
    if (lane < 32) Rh[(size_t)bh * 1024 + (qmin + l31 - 1024)] = full;
#pragma unroll
    for (int r = 0; r < 16; ++r) {
      const int crow = (r & 3) + 8 * (r >> 2) + 4 * hi;
      const int row = q0 + wid * 32 + crow;
      float* dst = &Oh[((size_t)bh * 1024 + (row - 1024)) * 64];
      dst[l31]      = oa0[r];
      dst[32 + l31] = oa1[r];
    }
  }
}

// ---------------------------------------------------------------------------
// Combine + normalize split-k partials: rows 1024..2047 of each (b,h).
// Ob[b, s, h*64+d] = (O0+O1)[bh, s-1024, d] / (R0+R1)[bh, s-1024].
// grid 4096 x 256; thread handles 4 d's (two float4 in, 8B bf16x4 out).
// ---------------------------------------------------------------------------
__global__ void attn_norm_kernel(const float* __restrict__ Oacc,
                                 const float* __restrict__ Racc,
                                 bf16_t* __restrict__ O) {
  constexpr size_t OHALF = (size_t)64 * 1024 * 64;
  constexpr size_t RHALF = (size_t)64 * 1024;
  const int g = blockIdx.x * 256 + threadIdx.x;   // [0, 64*1024*16)
  const int r = g >> 4;                           // packed row idx [0, 65536)
  const int dq = (g & 15) * 4;
  const int bh = r >> 10, srow = r & 1023;
  const int b = bh >> 4, h = bh & 15;
  const float4 v0 = *(const float4*)&Oacc[(size_t)r * 64 + dq];
  const float4 v1 = *(const float4*)&Oacc[OHALF + (size_t)r * 64 + dq];
  const float inv = __builtin_amdgcn_rcpf(Racc[r] + Racc[RHALF + r]);
  union { bf16_t hh[4]; uint2 u; } cv;
  cv.hh[0] = (bf16_t)((v0.x + v1.x) * inv);
  cv.hh[1] = (bf16_t)((v0.y + v1.y) * inv);
  cv.hh[2] = (bf16_t)((v0.z + v1.z) * inv);
  cv.hh[3] = (bf16_t)((v0.w + v1.w) * inv);
  const size_t off = ((size_t)(b * 2048 + 1024 + srow)) * 1024 + h * 64 + dq;
  *(uint2*)&O[off] = cv.u;
}

// ---------------------------------------------------------------------------
extern "C" void kernel_launch(void* const* d_in, const int* in_sizes, int n_in,
                              void* d_out, int out_size, void* d_ws, size_t ws_size,
                              hipStream_t stream) {
  // setup_inputs order: k, v, q, Wk, Wv, Wq, Wo  (all fp32)
  const float* k_in = (const float*)d_in[0];
  const float* v_in = (const float*)d_in[1];
  const float* q_in = (const float*)d_in[2];
  const float* Wk_in = (const float*)d_in[3];
  const float* Wv_in = (const float*)d_in[4];
  const float* Wq_in = (const float*)d_in[5];
  const float* Wo_in = (const float*)d_in[6];
  float* out = (float*)d_out;

  constexpr int    M = 8192, N = 1024, K = 1024;
  constexpr size_t SZ_X = (size_t)M * K * 2;
  constexpr size_t SZ_W = (size_t)N * K * 2;

  char* ws = (char*)d_ws;
  bf16_t* qb  = (bf16_t*)(ws);
  bf16_t* kb  = (bf16_t*)(ws + SZ_X);
  bf16_t* vb  = (bf16_t*)(ws + 2 * SZ_X);
  bf16_t* wkb = (bf16_t*)(ws + 3 * SZ_X);
  bf16_t* wvb = (bf16_t*)(ws + 3 * SZ_X + SZ_W);
  bf16_t* wqb = (bf16_t*)(ws + 3 * SZ_X + 2 * SZ_W);
  bf16_t* wob = (bf16_t*)(ws + 3 * SZ_X + 3 * SZ_W);
  bf16_t* Qp  = (bf16_t*)(ws + 3 * SZ_X + 4 * SZ_W);
  bf16_t* Kp  = (bf16_t*)(ws + 4 * SZ_X + 4 * SZ_W);
  bf16_t* Vtg = (bf16_t*)(ws + 5 * SZ_X + 4 * SZ_W);
  bf16_t* Ob  = qb;    // qb dead after Q projection
  // kb/vb dead after qkv: 2x16MB fp32 O-partials (plain stores, no init).
  // wkb/wvb dead after qkv: 2x256KB fp32 rowsum partials.
  float* Oacc = (float*)(ws + SZ_X);            // [2][64*1024*64] f32
  float* Racc = (float*)(ws + 3 * SZ_X);        // [2][64*1024] f32

  cvt_all_kernel<<<28672, 256, 0, stream>>>(q_in, k_in, v_in, Wk_in, Wv_in, Wq_in, Wo_in,
                                            (uint2*)ws);

  // Q scale = (1/sqrt(D)) * log2(e): scores in log2 domain for exp2 softmax
  qkv_kernel<<<dim3(64, 24), 256, 0, stream>>>(qb, kb, vb, wqb, wkb, wvb,
                                               Qp, Kp, Vtg, 0.125f * 1.44269504f);

  attn_kernel<<<dim3(24, 4 * 16), 256, 0, stream>>>(Qp, Kp, Vtg, Ob, Oacc, Racc);

  attn_norm_kernel<<<4096, 256, 0, stream>>>(Oacc, Racc, Ob);

  out_gemm_kernel<<<dim3(M / 128, N / 128), 256, 0, stream>>>(Ob, wob, out, M, N, K);
}

// Round 6
// 305.327 us; speedup vs baseline: 1.0659x; 1.0659x over previous
//
#include <hip/hip_runtime.h>

typedef __bf16 bf16_t;
typedef __bf16 bf16x8 __attribute__((ext_vector_type(8)));
typedef float f32x4 __attribute__((ext_vector_type(4)));
typedef float f32x16 __attribute__((ext_vector_type(16)));

// Problem constants: B=4, S=2048, E=1024, H=16, D=64

__device__ __forceinline__ void async_copy16(const void* g, void* l) {
  __builtin_amdgcn_global_load_lds(
      (const __attribute__((address_space(1))) void*)g,
      (__attribute__((address_space(3))) void*)l, 16, 0, 0);
}

__device__ __forceinline__ unsigned pk_bf16(float lo, float hi) {
  unsigned r;
  asm("v_cvt_pk_bf16_f32 %0, %1, %2" : "=v"(r) : "v"(lo), "v"(hi));
  return r;
}

// ---------------------------------------------------------------------------
// Fused fp32 -> bf16 convert for all 7 tensors (outputs contiguous in ws).
// ---------------------------------------------------------------------------
__global__ void cvt_all_kernel(const float* __restrict__ q, const float* __restrict__ k,
                               const float* __restrict__ v, const float* __restrict__ wk,
                               const float* __restrict__ wv, const float* __restrict__ wq,
                               const float* __restrict__ wo, uint2* __restrict__ out) {
  constexpr int QX = 2097152, QW = 262144;
  int g = blockIdx.x * 256 + threadIdx.x;
  const float* in; int off;
  if (g < QX)               { in = q;  off = 0; }
  else if (g < 2 * QX)      { in = k;  off = QX; }
  else if (g < 3 * QX)      { in = v;  off = 2 * QX; }
  else if (g < 3 * QX + QW)     { in = wk; off = 3 * QX; }
  else if (g < 3 * QX + 2 * QW) { in = wv; off = 3 * QX + QW; }
  else if (g < 3 * QX + 3 * QW) { in = wq; off = 3 * QX + 2 * QW; }
  else                          { in = wo; off = 3 * QX + 3 * QW; }
  float4 val = ((const float4*)in)[g - off];
  union { bf16_t h[4]; uint2 u; } cv;
  cv.h[0] = (bf16_t)val.x; cv.h[1] = (bf16_t)val.y;
  cv.h[2] = (bf16_t)val.z; cv.h[3] = (bf16_t)val.w;
  out[g] = cv.u;
}

// ---------------------------------------------------------------------------
// Fused Q/K/V projection GEMM. Grid (64, 24), 256 threads.
//  by>>3 == 0: Qp[B,H,S,D] = (qb @ Wq^T) * qscale
//  by>>3 == 1: Kp[B,H,S,D] =  kb @ Wk^T
//  by>>3 == 2: Vt[B,H,D,S] = (vb @ Wv^T)^T  (swapped operands)
// 128x128 tile, BK=32. LDS chunk placement XOR-swizzled (inverted at the
// global source; dest stays base+lane*16): fragment ds_read_b128 -> 2-way.
// ---------------------------------------------------------------------------
__global__ __launch_bounds__(256) void qkv_kernel(
    const bf16_t* __restrict__ qb, const bf16_t* __restrict__ kb, const bf16_t* __restrict__ vb,
    const bf16_t* __restrict__ wqb, const bf16_t* __restrict__ wkb, const bf16_t* __restrict__ wvb,
    bf16_t* __restrict__ Qp, bf16_t* __restrict__ Kp, bf16_t* __restrict__ Vt, float qscale)
{
  constexpr int K = 1024;
  __shared__ __align__(16) bf16_t As[128 * 32];
  __shared__ __align__(16) bf16_t Bs[128 * 32];
  const int tid  = threadIdx.x;
  const int lane = tid & 63;
  const int wid  = tid >> 6;
  const int quad = lane >> 4;
  const int l16  = lane & 15;
  const int bx = blockIdx.x, by = blockIdx.y;
  const int sel = by >> 3, sub = by & 7;
  const bf16_t *X, *W; bf16_t* Y; float scale = 1.0f;
  int m0, n0;
  if (sel == 0)      { X = qb;  W = wqb; Y = Qp; m0 = bx * 128; n0 = sub * 128; scale = qscale; }
  else if (sel == 1) { X = kb;  W = wkb; Y = Kp; m0 = bx * 128; n0 = sub * 128; }
  else               { X = wvb; W = vb;  Y = Vt; m0 = sub * 128; n0 = bx * 128; }
  const int wm = (wid >> 1) * 64;
  const int wn = (wid & 1) * 64;
  const int swz = quad ^ ((l16 >> 1) & 3);     // per-lane fragment swizzle

  f32x4 acc[4][4] = {};

  for (int k0 = 0; k0 < K; k0 += 32) {
#pragma unroll
    for (int p = 0; p < 2; ++p) {
      int c = tid + p * 256;                   // dest chunk (linear)
      int row = c >> 2;
      int seg = ((c & 3) ^ ((c >> 3) & 3)) * 8;  // swizzle-inverted source seg
      async_copy16(&X[(size_t)(m0 + row) * K + k0 + seg], (char*)As + (p * 256 + wid * 64) * 16);
      async_copy16(&W[(size_t)(n0 + row) * K + k0 + seg], (char*)Bs + (p * 256 + wid * 64) * 16);
    }
    __syncthreads();
    bf16x8 af[4], bfr[4];
#pragma unroll
    for (int i = 0; i < 4; ++i)
      af[i] = *(const bf16x8*)((const char*)As + ((wm + i * 16 + l16) * 4 + swz) * 16);
#pragma unroll
    for (int j = 0; j < 4; ++j)
      bfr[j] = *(const bf16x8*)((const char*)Bs + ((wn + j * 16 + l16) * 4 + swz) * 16);
#pragma unroll
    for (int i = 0; i < 4; ++i)
#pragma unroll
      for (int j = 0; j < 4; ++j)
        acc[i][j] = __builtin_amdgcn_mfma_f32_16x16x32_bf16(af[i], bfr[j], acc[i][j], 0, 0, 0);
    __syncthreads();
  }

#pragma unroll
  for (int i = 0; i < 4; ++i)
#pragma unroll
    for (int j = 0; j < 4; ++j)
#pragma unroll
      for (int r = 0; r < 4; ++r) {
        int row = m0 + wm + i * 16 + quad * 4 + r;
        int col = n0 + wn + j * 16 + l16;
        float val = acc[i][j][r] * scale;
        if (sel < 2) {                               // [B,H,S,D]
          int b = row >> 11, s = row & 2047;
          int h = col >> 6,  d = col & 63;
          Y[(((size_t)(b * 16 + h) << 11) + s) * 64 + d] = (bf16_t)val;
        } else {                                     // [B,H,D,S]
          int h = row >> 6,  d = row & 63;
          int b = col >> 11, s = col & 2047;
          Y[(((size_t)((b * 16 + h) * 64 + d)) << 11) + s] = (bf16_t)val;
        }
      }
}

// ---------------------------------------------------------------------------
// Output projection: out = Ob @ Wo^T, fp32 [M,N] row-major. Same swizzle.
// ---------------------------------------------------------------------------
__global__ __launch_bounds__(256) void out_gemm_kernel(
    const bf16_t* __restrict__ X, const bf16_t* __restrict__ W,
    float* __restrict__ Y, int M, int N, int K)
{
  __shared__ __align__(16) bf16_t As[128 * 32];
  __shared__ __align__(16) bf16_t Bs[128 * 32];
  const int tid  = threadIdx.x;
  const int lane = tid & 63;
  const int wid  = tid >> 6;
  const int quad = lane >> 4;
  const int l16  = lane & 15;
  const int m0 = blockIdx.x * 128;
  const int n0 = blockIdx.y * 128;
  const int wm = (wid >> 1) * 64;
  const int wn = (wid & 1) * 64;
  const int swz = quad ^ ((l16 >> 1) & 3);

  f32x4 acc[4][4] = {};

  for (int k0 = 0; k0 < K; k0 += 32) {
#pragma unroll
    for (int p = 0; p < 2; ++p) {
      int c = tid + p * 256;
      int row = c >> 2;
      int seg = ((c & 3) ^ ((c >> 3) & 3)) * 8;
      async_copy16(&X[(size_t)(m0 + row) * K + k0 + seg], (char*)As + (p * 256 + wid * 64) * 16);
      async_copy16(&W[(size_t)(n0 + row) * K + k0 + seg], (char*)Bs + (p * 256 + wid * 64) * 16);
    }
    __syncthreads();
    bf16x8 af[4], bfr[4];
#pragma unroll
    for (int i = 0; i < 4; ++i)
      af[i] = *(const bf16x8*)((const char*)As + ((wm + i * 16 + l16) * 4 + swz) * 16);
#pragma unroll
    for (int j = 0; j < 4; ++j)
      bfr[j] = *(const bf16x8*)((const char*)Bs + ((wn + j * 16 + l16) * 4 + swz) * 16);
#pragma unroll
    for (int i = 0; i < 4; ++i)
#pragma unroll
      for (int j = 0; j < 4; ++j)
        acc[i][j] = __builtin_amdgcn_mfma_f32_16x16x32_bf16(af[i], bfr[j], acc[i][j], 0, 0, 0);
    __syncthreads();
  }

#pragma unroll
  for (int i = 0; i < 4; ++i)
#pragma unroll
    for (int j = 0; j < 4; ++j)
#pragma unroll
      for (int r = 0; r < 4; ++r) {
        int row = m0 + wm + i * 16 + quad * 4 + r;
        int col = n0 + wn + j * 16 + l16;
        Y[(size_t)row * N + col] = acc[i][j][r];
      }
}

// ---------------------------------------------------------------------------
// Causal flash attention, v4b: swapped QK^T + in-register softmax + split-k
// (deterministic combine) + LPT dispatch + counted-vmcnt pipeline.
//  - 1-D grid 1536: rank = bx>>6 indexes chunk table sorted by descending
//    steps (LPT: heavy chunks dispatch first); bh = bx&63, so all chunks of
//    one bh share bx%8 -> same XCD L2 (K/V fetched once per XCD).
//  - K triple-buffered (staged 2 steps ahead), V double-buffered (1 ahead).
//    Raw s_barrier + counted s_waitcnt vmcnt(4/6) gates (never 0 mid-loop,
//    T3/T4): one K prefetch always in flight across barriers.
//    Issue order per iter t (after top barrier): V(t+1) then K(t+2); 2
//    global_load_lds instr per tile per thread. Gate derivation:
//      top:  outstanding K(t),V(t),K(t+1) -> vmcnt(4) leaves K(t) done
//      mid:  + V(t+1),K(t+2) issued -> vmcnt(6) leaves V(t) done
//    Each gate is [own-wait, s_barrier] so all waves' loads are covered.
//    sched_barrier(0) after each gate pins LDS reads below it (rule #18:
//    hipcc may hoist past inline-asm waits despite "memory" clobber).
//  - LDS 40960 B (3K+2V bufs) -> 4 blocks/CU; rsbuf aliases dead Ks in
//    the epilogue.
// ---------------------------------------------------------------------------
__global__ __launch_bounds__(256, 3) void attn_kernel(
    const bf16_t* __restrict__ Qp, const bf16_t* __restrict__ Kp,
    const bf16_t* __restrict__ Vt, bf16_t* __restrict__ O,
    float* __restrict__ Oacc, float* __restrict__ Racc)
{
  constexpr int S = 2048, D = 64, E = 1024;
  constexpr int BQ = 128, BK = 64;
  __shared__ __align__(16) bf16_t Ks[3][8 * 64 * 8];   // [buf][panel=d>>3][krow][8]
  __shared__ __align__(16) bf16_t Vs[2][8 * 64 * 8];   // [buf][panel=k>>3][drow][8]
  float* rsbuf = (float*)Ks;                           // epilogue overlay (Ks dead)

  const int tid = threadIdx.x, lane = tid & 63, wid = tid >> 6;
  const int l31 = lane & 31, hi = lane >> 5;

  // ---- LPT chunk table: rank -> (qt, half|whole), steps descending -------
  // steps: 16,16,16,15,15,14,14,14,13,13,12,12,12,11,11,10,10,10,9,9,8,6,4,2
  const signed char QT_TAB[24] = {15,15,7,14,14,13,13,6,12,12,11,11,5,10,10,9,9,4,8,8,3,2,1,0};
  const signed char HF_TAB[24] = {0,1,2,0,1,0,1,2,0,1,0,1,2,0,1,0,1,2,0,1,2,2,2,2};
  const int rank = (int)blockIdx.x >> 6;
  const int bh   = (int)blockIdx.x & 63;
  const int b = bh >> 4, h = bh & 15;
  const int qt = QT_TAB[rank];
  const int hf = HF_TAB[rank];
  const int nks = 2 * qt + 2;
  int s0, s1, half; bool direct;
  if (hf == 2) { s0 = 0; s1 = nks; half = 0; direct = true; }
  else         { half = hf; s0 = half ? nks / 2 : 0; s1 = half ? nks : nks / 2; direct = false; }

  const int q0 = qt * BQ;
  const size_t base  = (size_t)bh * S * D;
  const size_t baseV = (size_t)bh * D * S;
  const int qmin = q0 + wid * 32;
  const int qmax = qmin + 31;

  // Q fragments (B-operand): lane holds Q[qmin+l31][ks*16 + hi*8 + j]
  bf16x8 qf[4];
#pragma unroll
  for (int ks = 0; ks < 4; ++ks)
    qf[ks] = *(const bf16x8*)&Qp[base + (size_t)(qmin + l31) * D + ks * 16 + hi * 8];

  auto stageK = [&](int kt, int buf) {
#pragma unroll
    for (int is = 0; is < 2; ++is) {
      const int c = is * 256 + tid;
      const int p = c >> 6, row = c & 63;
      async_copy16(&Kp[base + (size_t)(kt * BK + row) * D + p * 8],
                   (char*)Ks[buf] + (is * 256 + wid * 64) * 16);
    }
  };
  auto stageV = [&](int kt, int buf) {
#pragma unroll
    for (int is = 0; is < 2; ++is) {
      const int c = is * 256 + tid;
      const int p = c >> 6, row = c & 63;
      async_copy16(&Vt[baseV + (size_t)row * S + kt * BK + p * 8],
                   (char*)Vs[buf] + (is * 256 + wid * 64) * 16);
    }
  };

  // prologue: queue order (oldest->newest) = K(s0), V(s0), K(s0+1)
  stageK(s0, s0 % 3);
  stageV(s0, s0 & 1);
  if (s0 + 1 < s1) stageK(s0 + 1, (s0 + 1) % 3);

  const f32x16 z16 = {};
  f32x16 oa0 = {}, oa1 = {};
  float rs = 0.0f;

  for (int kt = s0; kt < s1; ++kt) {
    const int k0 = kt * BK;
    const bool live = (k0 <= qmax);        // wave-uniform causal skip
    // ---- top gate: K(kt) landed in all waves ---------------------------
    if (kt + 1 < s1) { asm volatile("s_waitcnt vmcnt(4)" ::: "memory"); }
    else             { asm volatile("s_waitcnt vmcnt(2)" ::: "memory"); }
    __builtin_amdgcn_s_barrier();
    __builtin_amdgcn_sched_barrier(0);
    // ---- issue next stages (buffers freed by barrier above) ------------
    if (kt + 1 < s1) stageV(kt + 1, (kt + 1) & 1);
    if (kt + 2 < s1) stageK(kt + 2, (kt + 2) % 3);

    unsigned pw[16];
    if (live) {
      const bf16_t* ksb = Ks[kt % 3];
      // ---- S^T = K Q^T (swapped): sc{0,1} = k-blocks 0..31 / 32..63 ----
      f32x16 sc0, sc1;
      {
        const bf16x8 kf0 = *(const bf16x8*)&ksb[(hi * 64 + l31) * 8];
        const bf16x8 kf1 = *(const bf16x8*)&ksb[(hi * 64 + 32 + l31) * 8];
        sc0 = __builtin_amdgcn_mfma_f32_32x32x16_bf16(kf0, qf[0], z16, 0, 0, 0);
        sc1 = __builtin_amdgcn_mfma_f32_32x32x16_bf16(kf1, qf[0], z16, 0, 0, 0);
      }
#pragma unroll
      for (int ks = 1; ks < 4; ++ks) {
        const bf16x8 kf0 = *(const bf16x8*)&ksb[((ks * 2 + hi) * 64 + l31) * 8];
        const bf16x8 kf1 = *(const bf16x8*)&ksb[((ks * 2 + hi) * 64 + 32 + l31) * 8];
        sc0 = __builtin_amdgcn_mfma_f32_32x32x16_bf16(kf0, qf[ks], sc0, 0, 0, 0);
        sc1 = __builtin_amdgcn_mfma_f32_32x32x16_bf16(kf1, qf[ks], sc1, 0, 0, 0);
      }
      // ---- causal mask (value compare, compile-time reg indices) -------
      if (k0 + 63 > qmin) {
        const int qg = qmin + l31;
#pragma unroll
        for (int r = 0; r < 16; ++r) {
          const int kg = k0 + (r & 3) + 8 * (r >> 2) + 4 * hi;
          if (kg > qg)      sc0[r] = -1e30f;
          if (kg + 32 > qg) sc1[r] = -1e30f;
        }
      }
      // ---- P = exp2(S) in place ----------------------------------------
#pragma unroll
      for (int r = 0; r < 16; ++r) {
        sc0[r] = __builtin_amdgcn_exp2f(sc0[r]);
        sc1[r] = __builtin_amdgcn_exp2f(sc1[r]);
      }
      // ---- rowsum (this lane's k-half of column q = qmin+l31) ----------
      {
        float s0a = 0.f, s1a = 0.f, s2a = 0.f, s3a = 0.f;
#pragma unroll
        for (int r = 0; r < 16; r += 4) {
          s0a += sc0[r]     + sc1[r];
          s1a += sc0[r + 1] + sc1[r + 1];
          s2a += sc0[r + 2] + sc1[r + 2];
          s3a += sc0[r + 3] + sc1[r + 3];
        }
        rs += (s0a + s1a) + (s2a + s3a);
      }
      // ---- pack P -> PV A-fragments (cvt_pk + permlane32_swap) ---------
      // swap(dst=low-k, src=high-k): dst -> {dst.lo, src.lo} = frag word0,
      //                              src -> {dst.hi, src.hi} = frag word2.
      {
        unsigned a0 = pk_bf16(sc0[0], sc0[1]),   a1 = pk_bf16(sc0[2], sc0[3]);
        unsigned b0 = pk_bf16(sc0[4], sc0[5]),   b1 = pk_bf16(sc0[6], sc0[7]);
        unsigned c0 = pk_bf16(sc0[8], sc0[9]),   c1 = pk_bf16(sc0[10], sc0[11]);
        unsigned d0 = pk_bf16(sc0[12], sc0[13]), d1 = pk_bf16(sc0[14], sc0[15]);
        asm("v_permlane32_swap_b32 %0, %1" : "+v"(a0), "+v"(b0));
        asm("v_permlane32_swap_b32 %0, %1" : "+v"(a1), "+v"(b1));
        asm("v_permlane32_swap_b32 %0, %1" : "+v"(c0), "+v"(d0));
        asm("v_permlane32_swap_b32 %0, %1" : "+v"(c1), "+v"(d1));
        pw[0] = a0; pw[1] = a1; pw[2] = b0; pw[3] = b1;
        pw[4] = c0; pw[5] = c1; pw[6] = d0; pw[7] = d1;
      }
      {
        unsigned a0 = pk_bf16(sc1[0], sc1[1]),   a1 = pk_bf16(sc1[2], sc1[3]);
        unsigned b0 = pk_bf16(sc1[4], sc1[5]),   b1 = pk_bf16(sc1[6], sc1[7]);
        unsigned c0 = pk_bf16(sc1[8], sc1[9]),   c1 = pk_bf16(sc1[10], sc1[11]);
        unsigned d0 = pk_bf16(sc1[12], sc1[13]), d1 = pk_bf16(sc1[14], sc1[15]);
        asm("v_permlane32_swap_b32 %0, %1" : "+v"(a0), "+v"(b0));
        asm("v_permlane32_swap_b32 %0, %1" : "+v"(a1), "+v"(b1));
        asm("v_permlane32_swap_b32 %0, %1" : "+v"(c0), "+v"(d0));
        asm("v_permlane32_swap_b32 %0, %1" : "+v"(c1), "+v"(d1));
        pw[8]  = a0; pw[9]  = a1; pw[10] = b0; pw[11] = b1;
        pw[12] = c0; pw[13] = c1; pw[14] = d0; pw[15] = d1;
      }
    }
    // ---- mid gate: V(kt) landed in all waves (uniform, outside `live`) --
    if (kt + 2 < s1)      { asm volatile("s_waitcnt vmcnt(6)" ::: "memory"); }
    else if (kt + 1 < s1) { asm volatile("s_waitcnt vmcnt(4)" ::: "memory"); }
    else                  { asm volatile("s_waitcnt vmcnt(0)" ::: "memory"); }
    __builtin_amdgcn_s_barrier();
    __builtin_amdgcn_sched_barrier(0);
    if (live) {
      const bf16_t* vsb = Vs[kt & 1];
      // ---- O += P V ----------------------------------------------------
      union U8 { unsigned u[4]; bf16x8 v; };
#pragma unroll
      for (int kb = 0; kb < 2; ++kb)
#pragma unroll
        for (int ks2 = 0; ks2 < 2; ++ks2) {
          U8 pu;
          pu.u[0] = pw[kb * 8 + ks2 * 4 + 0];
          pu.u[1] = pw[kb * 8 + ks2 * 4 + 1];
          pu.u[2] = pw[kb * 8 + ks2 * 4 + 2];
          pu.u[3] = pw[kb * 8 + ks2 * 4 + 3];
          const int pnl = kb * 4 + ks2 * 2 + hi;
          const bf16x8 vf0 = *(const bf16x8*)&vsb[(pnl * 64 + l31) * 8];
          const bf16x8 vf1 = *(const bf16x8*)&vsb[(pnl * 64 + 32 + l31) * 8];
          oa0 = __builtin_amdgcn_mfma_f32_32x32x16_bf16(pu.v, vf0, oa0, 0, 0, 0);
          oa1 = __builtin_amdgcn_mfma_f32_32x32x16_bf16(pu.v, vf1, oa1, 0, 0, 0);
        }
    }
  }

  // ---- epilogue ----------------------------------------------------------
  const float full = rs + __shfl(rs, lane ^ 32);
  if (direct) {
    // combine k-halves of rowsum via LDS broadcast (rsbuf aliases dead Ks)
    __syncthreads();                       // all waves out of main loop
    if (lane < 32) rsbuf[wid * 32 + l31] = full;
    __syncthreads();
#pragma unroll
    for (int r = 0; r < 16; ++r) {
      const int crow = (r & 3) + 8 * (r >> 2) + 4 * hi;
      const float inv = __builtin_amdgcn_rcpf(rsbuf[wid * 32 + crow]);
      const int row = q0 + wid * 32 + crow;
      const size_t rowoff = ((size_t)(b * S + row)) * E + h * D;
      O[rowoff + l31]      = (bf16_t)(oa0[r] * inv);
      O[rowoff + 32 + l31] = (bf16_t)(oa1[r] * inv);
    }
  } else {
    // plain-store partials (rows 1024..2047), buffer selected by k-half
    float* Oh = Oacc + (size_t)half * (64 * 1024 * 64);
    float* Rh = Racc + (size_t)half * (64 * 1024);
    if (lane < 32) Rh[(size_t)bh * 1024 + (qmin + l31 - 1024)] = full;
#pragma unroll
    for (int r = 0; r < 16; ++r) {
      const int crow = (r & 3) + 8 * (r >> 2) + 4 * hi;
      const int row = q0 + wid * 32 + crow;
      float* dst = &Oh[((size_t)bh * 1024 + (row - 1024)) * 64];
      dst[l31]      = oa0[r];
      dst[32 + l31] = oa1[r];
    }
  }
}

// ---------------------------------------------------------------------------
// Combine + normalize split-k partials: rows 1024..2047 of each (b,h).
// Ob[b, s, h*64+d] = (O0+O1)[bh, s-1024, d] / (R0+R1)[bh, s-1024].
// grid 4096 x 256; thread handles 4 d's (two float4 in, 8B bf16x4 out).
// ---------------------------------------------------------------------------
__global__ void attn_norm_kernel(const float* __restrict__ Oacc,
                                 const float* __restrict__ Racc,
                                 bf16_t* __restrict__ O) {
  constexpr size_t OHALF = (size_t)64 * 1024 * 64;
  constexpr size_t RHALF = (size_t)64 * 1024;
  const int g = blockIdx.x * 256 + threadIdx.x;   // [0, 64*1024*16)
  const int r = g >> 4;                           // packed row idx [0, 65536)
  const int dq = (g & 15) * 4;
  const int bh = r >> 10, srow = r & 1023;
  const int b = bh >> 4, h = bh & 15;
  const float4 v0 = *(const float4*)&Oacc[(size_t)r * 64 + dq];
  const float4 v1 = *(const float4*)&Oacc[OHALF + (size_t)r * 64 + dq];
  const float inv = __builtin_amdgcn_rcpf(Racc[r] + Racc[RHALF + r]);
  union { bf16_t hh[4]; uint2 u; } cv;
  cv.hh[0] = (bf16_t)((v0.x + v1.x) * inv);
  cv.hh[1] = (bf16_t)((v0.y + v1.y) * inv);
  cv.hh[2] = (bf16_t)((v0.z + v1.z) * inv);
  cv.hh[3] = (bf16_t)((v0.w + v1.w) * inv);
  const size_t off = ((size_t)(b * 2048 + 1024 + srow)) * 1024 + h * 64 + dq;
  *(uint2*)&O[off] = cv.u;
}

// ---------------------------------------------------------------------------
extern "C" void kernel_launch(void* const* d_in, const int* in_sizes, int n_in,
                              void* d_out, int out_size, void* d_ws, size_t ws_size,
                              hipStream_t stream) {
  // setup_inputs order: k, v, q, Wk, Wv, Wq, Wo  (all fp32)
  const float* k_in = (const float*)d_in[0];
  const float* v_in = (const float*)d_in[1];
  const float* q_in = (const float*)d_in[2];
  const float* Wk_in = (const float*)d_in[3];
  const float* Wv_in = (const float*)d_in[4];
  const float* Wq_in = (const float*)d_in[5];
  const float* Wo_in = (const float*)d_in[6];
  float* out = (float*)d_out;

  constexpr int    M = 8192, N = 1024, K = 1024;
  constexpr size_t SZ_X = (size_t)M * K * 2;
  constexpr size_t SZ_W = (size_t)N * K * 2;

  char* ws = (char*)d_ws;
  bf16_t* qb  = (bf16_t*)(ws);
  bf16_t* kb  = (bf16_t*)(ws + SZ_X);
  bf16_t* vb  = (bf16_t*)(ws + 2 * SZ_X);
  bf16_t* wkb = (bf16_t*)(ws + 3 * SZ_X);
  bf16_t* wvb = (bf16_t*)(ws + 3 * SZ_X + SZ_W);
  bf16_t* wqb = (bf16_t*)(ws + 3 * SZ_X + 2 * SZ_W);
  bf16_t* wob = (bf16_t*)(ws + 3 * SZ_X + 3 * SZ_W);
  bf16_t* Qp  = (bf16_t*)(ws + 3 * SZ_X + 4 * SZ_W);
  bf16_t* Kp  = (bf16_t*)(ws + 4 * SZ_X + 4 * SZ_W);
  bf16_t* Vtg = (bf16_t*)(ws + 5 * SZ_X + 4 * SZ_W);
  bf16_t* Ob  = qb;    // qb dead after Q projection
  // kb/vb dead after qkv: 2x16MB fp32 O-partials (plain stores, no init).
  // wkb/wvb dead after qkv: 2x256KB fp32 rowsum partials.
  float* Oacc = (float*)(ws + SZ_X);            // [2][64*1024*64] f32
  float* Racc = (float*)(ws + 3 * SZ_X);        // [2][64*1024] f32

  cvt_all_kernel<<<28672, 256, 0, stream>>>(q_in, k_in, v_in, Wk_in, Wv_in, Wq_in, Wo_in,
                                            (uint2*)ws);

  // Q scale = (1/sqrt(D)) * log2(e): scores in log2 domain for exp2 softmax
  qkv_kernel<<<dim3(64, 24), 256, 0, stream>>>(qb, kb, vb, wqb, wkb, wvb,
                                               Qp, Kp, Vtg, 0.125f * 1.44269504f);

  attn_kernel<<<dim3(1536), 256, 0, stream>>>(Qp, Kp, Vtg, Ob, Oacc, Racc);

  attn_norm_kernel<<<4096, 256, 0, stream>>>(Oacc, Racc, Ob);

  out_gemm_kernel<<<dim3(M / 128, N / 128), 256, 0, stream>>>(Ob, wob, out, M, N, K);
}

// Round 8
// 299.613 us; speedup vs baseline: 1.0862x; 1.0191x over previous
//
#include <hip/hip_runtime.h>

typedef __bf16 bf16_t;
typedef __bf16 bf16x8 __attribute__((ext_vector_type(8)));
typedef float f32x4 __attribute__((ext_vector_type(4)));
typedef float f32x16 __attribute__((ext_vector_type(16)));

// Problem constants: B=4, S=2048, E=1024, H=16, D=64

__device__ __forceinline__ void async_copy16(const void* g, void* l) {
  __builtin_amdgcn_global_load_lds(
      (const __attribute__((address_space(1))) void*)g,
      (__attribute__((address_space(3))) void*)l, 16, 0, 0);
}

__device__ __forceinline__ unsigned pk_bf16(float lo, float hi) {
  unsigned r;
  asm("v_cvt_pk_bf16_f32 %0, %1, %2" : "=v"(r) : "v"(lo), "v"(hi));
  return r;
}

// ---------------------------------------------------------------------------
// Fused fp32 -> bf16 convert for all 7 tensors (outputs contiguous in ws).
// ---------------------------------------------------------------------------
__global__ void cvt_all_kernel(const float* __restrict__ q, const float* __restrict__ k,
                               const float* __restrict__ v, const float* __restrict__ wk,
                               const float* __restrict__ wv, const float* __restrict__ wq,
                               const float* __restrict__ wo, uint2* __restrict__ out) {
  constexpr int QX = 2097152, QW = 262144;
  int g = blockIdx.x * 256 + threadIdx.x;
  const float* in; int off;
  if (g < QX)               { in = q;  off = 0; }
  else if (g < 2 * QX)      { in = k;  off = QX; }
  else if (g < 3 * QX)      { in = v;  off = 2 * QX; }
  else if (g < 3 * QX + QW)     { in = wk; off = 3 * QX; }
  else if (g < 3 * QX + 2 * QW) { in = wv; off = 3 * QX + QW; }
  else if (g < 3 * QX + 3 * QW) { in = wq; off = 3 * QX + 2 * QW; }
  else                          { in = wo; off = 3 * QX + 3 * QW; }
  float4 val = ((const float4*)in)[g - off];
  union { bf16_t h[4]; uint2 u; } cv;
  cv.h[0] = (bf16_t)val.x; cv.h[1] = (bf16_t)val.y;
  cv.h[2] = (bf16_t)val.z; cv.h[3] = (bf16_t)val.w;
  out[g] = cv.u;
}

// ---------------------------------------------------------------------------
// Fused Q/K/V projection GEMM, v2: triple-buffered counted-vmcnt pipeline
// (1 barrier/K-step, loads always in flight) + XCD-grouped 1-D grid.
// Grid 1536: wg = (g&7) + 8*sub + 64*(g>>3) where g = sel*64 + bx, sub = N-tile.
// All 8 subs of one (sel,bx) share wg%8 -> same XCD L2 (shared X panel).
//  sel 0: Qp[B,H,S,D] = (qb @ Wq^T) * qscale
//  sel 1: Kp[B,H,S,D] =  kb @ Wk^T
//  sel 2: Vt[B,H,D,S] = (vb @ Wv^T)^T  (swapped operands)
// 128x128 tile, BK=32. LDS chunk placement XOR-swizzled (inverted at the
// global source; dest stays base+lane*16): fragment ds_read_b128 -> 2-way.
// Pipeline ledger: prologue S(0),S(1) (4 loads each); top of step kt queue =
// {S(kt):4, S(kt+1):4} -> vmcnt(4) completes S(kt); after barrier stage
// S(kt+2) into buf (kt+2)%3 (all waves finished reading it at step kt-1).
// ---------------------------------------------------------------------------
__global__ __launch_bounds__(256, 3) void qkv_kernel(
    const bf16_t* __restrict__ qb, const bf16_t* __restrict__ kb, const bf16_t* __restrict__ vb,
    const bf16_t* __restrict__ wqb, const bf16_t* __restrict__ wkb, const bf16_t* __restrict__ wvb,
    bf16_t* __restrict__ Qp, bf16_t* __restrict__ Kp, bf16_t* __restrict__ Vt, float qscale)
{
  constexpr int K = 1024, NKT = 32;
  __shared__ __align__(16) bf16_t As[3][128 * 32];
  __shared__ __align__(16) bf16_t Bs[3][128 * 32];
  const int tid  = threadIdx.x;
  const int lane = tid & 63;
  const int wid  = tid >> 6;
  const int quad = lane >> 4;
  const int l16  = lane & 15;
  // XCD-grouped decode
  const int wg  = (int)blockIdx.x;
  const int g   = (wg & 7) + ((wg >> 6) << 3);   // g = sel*64 + bx
  const int sub = (wg >> 3) & 7;
  const int sel = g >> 6;
  const int bx  = g & 63;
  const bf16_t *X, *W; bf16_t* Y; float scale = 1.0f;
  int m0, n0;
  if (sel == 0)      { X = qb;  W = wqb; Y = Qp; m0 = bx * 128; n0 = sub * 128; scale = qscale; }
  else if (sel == 1) { X = kb;  W = wkb; Y = Kp; m0 = bx * 128; n0 = sub * 128; }
  else               { X = wvb; W = vb;  Y = Vt; m0 = sub * 128; n0 = bx * 128; }
  const int wm = (wid >> 1) * 64;
  const int wn = (wid & 1) * 64;
  const int swz = quad ^ ((l16 >> 1) & 3);     // per-lane fragment swizzle

  auto stage = [&](int kt, int buf) {
    const int k0 = kt * 32;
#pragma unroll
    for (int p = 0; p < 2; ++p) {
      int c = tid + p * 256;                   // dest chunk (linear)
      int row = c >> 2;
      int seg = ((c & 3) ^ ((c >> 3) & 3)) * 8;  // swizzle-inverted source seg
      async_copy16(&X[(size_t)(m0 + row) * K + k0 + seg],
                   (char*)As[buf] + (p * 256 + wid * 64) * 16);
      async_copy16(&W[(size_t)(n0 + row) * K + k0 + seg],
                   (char*)Bs[buf] + (p * 256 + wid * 64) * 16);
    }
  };

  // prologue: 2 tiles in flight
  stage(0, 0);
  stage(1, 1);

  f32x4 acc[4][4] = {};

  for (int kt = 0; kt < NKT; ++kt) {
    // gate: S(kt) landed; S(kt+1) stays in flight (never drain mid-loop)
    if (kt + 1 < NKT) { asm volatile("s_waitcnt vmcnt(4)" ::: "memory"); }
    else              { asm volatile("s_waitcnt vmcnt(0)" ::: "memory"); }
    __builtin_amdgcn_s_barrier();
    __builtin_amdgcn_sched_barrier(0);
    if (kt + 2 < NKT) stage(kt + 2, (kt + 2) % 3);

    const bf16_t* as = As[kt % 3];
    const bf16_t* bs = Bs[kt % 3];
    bf16x8 af[4], bfr[4];
#pragma unroll
    for (int i = 0; i < 4; ++i)
      af[i] = *(const bf16x8*)((const char*)as + ((wm + i * 16 + l16) * 4 + swz) * 16);
#pragma unroll
    for (int j = 0; j < 4; ++j)
      bfr[j] = *(const bf16x8*)((const char*)bs + ((wn + j * 16 + l16) * 4 + swz) * 16);
#pragma unroll
    for (int i = 0; i < 4; ++i)
#pragma unroll
      for (int j = 0; j < 4; ++j)
        acc[i][j] = __builtin_amdgcn_mfma_f32_16x16x32_bf16(af[i], bfr[j], acc[i][j], 0, 0, 0);
  }

#pragma unroll
  for (int i = 0; i < 4; ++i)
#pragma unroll
    for (int j = 0; j < 4; ++j)
#pragma unroll
      for (int r = 0; r < 4; ++r) {
        int row = m0 + wm + i * 16 + quad * 4 + r;
        int col = n0 + wn + j * 16 + l16;
        float val = acc[i][j][r] * scale;
        if (sel < 2) {                               // [B,H,S,D]
          int b = row >> 11, s = row & 2047;
          int h = col >> 6,  d = col & 63;
          Y[(((size_t)(b * 16 + h) << 11) + s) * 64 + d] = (bf16_t)val;
        } else {                                     // [B,H,D,S]
          int h = row >> 6,  d = row & 63;
          int b = col >> 11, s = col & 2047;
          Y[(((size_t)((b * 16 + h) * 64 + d)) << 11) + s] = (bf16_t)val;
        }
      }
}

// ---------------------------------------------------------------------------
// Output projection, v2: same triple-buffered counted-vmcnt pipeline + XCD
// grouping. Grid 512: wg = (bx&7) + 8*by + 64*(bx>>3); 8 by's of one bx
// (shared X panel) share wg%8. out = Ob @ Wo^T, fp32 [M,N] row-major.
// ---------------------------------------------------------------------------
__global__ __launch_bounds__(256, 3) void out_gemm_kernel(
    const bf16_t* __restrict__ X, const bf16_t* __restrict__ W,
    float* __restrict__ Y, int M, int N, int K)
{
  constexpr int NKT = 32;
  __shared__ __align__(16) bf16_t As[3][128 * 32];
  __shared__ __align__(16) bf16_t Bs[3][128 * 32];
  const int tid  = threadIdx.x;
  const int lane = tid & 63;
  const int wid  = tid >> 6;
  const int quad = lane >> 4;
  const int l16  = lane & 15;
  const int wg = (int)blockIdx.x;
  const int bx = (wg & 7) + ((wg >> 6) << 3);
  const int by = (wg >> 3) & 7;
  const int m0 = bx * 128;
  const int n0 = by * 128;
  const int wm = (wid >> 1) * 64;
  const int wn = (wid & 1) * 64;
  const int swz = quad ^ ((l16 >> 1) & 3);

  auto stage = [&](int kt, int buf) {
    const int k0 = kt * 32;
#pragma unroll
    for (int p = 0; p < 2; ++p) {
      int c = tid + p * 256;
      int row = c >> 2;
      int seg = ((c & 3) ^ ((c >> 3) & 3)) * 8;
      async_copy16(&X[(size_t)(m0 + row) * K + k0 + seg],
                   (char*)As[buf] + (p * 256 + wid * 64) * 16);
      async_copy16(&W[(size_t)(n0 + row) * K + k0 + seg],
                   (char*)Bs[buf] + (p * 256 + wid * 64) * 16);
    }
  };

  stage(0, 0);
  stage(1, 1);

  f32x4 acc[4][4] = {};

  for (int kt = 0; kt < NKT; ++kt) {
    if (kt + 1 < NKT) { asm volatile("s_waitcnt vmcnt(4)" ::: "memory"); }
    else              { asm volatile("s_waitcnt vmcnt(0)" ::: "memory"); }
    __builtin_amdgcn_s_barrier();
    __builtin_amdgcn_sched_barrier(0);
    if (kt + 2 < NKT) stage(kt + 2, (kt + 2) % 3);

    const bf16_t* as = As[kt % 3];
    const bf16_t* bs = Bs[kt % 3];
    bf16x8 af[4], bfr[4];
#pragma unroll
    for (int i = 0; i < 4; ++i)
      af[i] = *(const bf16x8*)((const char*)as + ((wm + i * 16 + l16) * 4 + swz) * 16);
#pragma unroll
    for (int j = 0; j < 4; ++j)
      bfr[j] = *(const bf16x8*)((const char*)bs + ((wn + j * 16 + l16) * 4 + swz) * 16);
#pragma unroll
    for (int i = 0; i < 4; ++i)
#pragma unroll
      for (int j = 0; j < 4; ++j)
        acc[i][j] = __builtin_amdgcn_mfma_f32_16x16x32_bf16(af[i], bfr[j], acc[i][j], 0, 0, 0);
  }

#pragma unroll
  for (int i = 0; i < 4; ++i)
#pragma unroll
    for (int j = 0; j < 4; ++j)
#pragma unroll
      for (int r = 0; r < 4; ++r) {
        int row = m0 + wm + i * 16 + quad * 4 + r;
        int col = n0 + wn + j * 16 + l16;
        Y[(size_t)row * N + col] = acc[i][j][r];
      }
}

// ---------------------------------------------------------------------------
// Causal flash attention, v4b (unchanged from round 6 — passing): swapped
// QK^T + in-register softmax + split-k (deterministic combine) + LPT
// dispatch + counted-vmcnt pipeline.
// ---------------------------------------------------------------------------
__global__ __launch_bounds__(256, 3) void attn_kernel(
    const bf16_t* __restrict__ Qp, const bf16_t* __restrict__ Kp,
    const bf16_t* __restrict__ Vt, bf16_t* __restrict__ O,
    float* __restrict__ Oacc, float* __restrict__ Racc)
{
  constexpr int S = 2048, D = 64, E = 1024;
  constexpr int BQ = 128, BK = 64;
  __shared__ __align__(16) bf16_t Ks[3][8 * 64 * 8];   // [buf][panel=d>>3][krow][8]
  __shared__ __align__(16) bf16_t Vs[2][8 * 64 * 8];   // [buf][panel=k>>3][drow][8]
  float* rsbuf = (float*)Ks;                           // epilogue overlay (Ks dead)

  const int tid = threadIdx.x, lane = tid & 63, wid = tid >> 6;
  const int l31 = lane & 31, hi = lane >> 5;

  // ---- LPT chunk table: rank -> (qt, half|whole), steps descending -------
  const signed char QT_TAB[24] = {15,15,7,14,14,13,13,6,12,12,11,11,5,10,10,9,9,4,8,8,3,2,1,0};
  const signed char HF_TAB[24] = {0,1,2,0,1,0,1,2,0,1,0,1,2,0,1,0,1,2,0,1,2,2,2,2};
  const int rank = (int)blockIdx.x >> 6;
  const int bh   = (int)blockIdx.x & 63;
  const int b = bh >> 4, h = bh & 15;
  const int qt = QT_TAB[rank];
  const int hf = HF_TAB[rank];
  const int nks = 2 * qt + 2;
  int s0, s1, half; bool direct;
  if (hf == 2) { s0 = 0; s1 = nks; half = 0; direct = true; }
  else         { half = hf; s0 = half ? nks / 2 : 0; s1 = half ? nks : nks / 2; direct = false; }

  const int q0 = qt * BQ;
  const size_t base  = (size_t)bh * S * D;
  const size_t baseV = (size_t)bh * D * S;
  const int qmin = q0 + wid * 32;
  const int qmax = qmin + 31;

  // Q fragments (B-operand): lane holds Q[qmin+l31][ks*16 + hi*8 + j]
  bf16x8 qf[4];
#pragma unroll
  for (int ks = 0; ks < 4; ++ks)
    qf[ks] = *(const bf16x8*)&Qp[base + (size_t)(qmin + l31) * D + ks * 16 + hi * 8];

  auto stageK = [&](int kt, int buf) {
#pragma unroll
    for (int is = 0; is < 2; ++is) {
      const int c = is * 256 + tid;
      const int p = c >> 6, row = c & 63;
      async_copy16(&Kp[base + (size_t)(kt * BK + row) * D + p * 8],
                   (char*)Ks[buf] + (is * 256 + wid * 64) * 16);
    }
  };
  auto stageV = [&](int kt, int buf) {
#pragma unroll
    for (int is = 0; is < 2; ++is) {
      const int c = is * 256 + tid;
      const int p = c >> 6, row = c & 63;
      async_copy16(&Vt[baseV + (size_t)row * S + kt * BK + p * 8],
                   (char*)Vs[buf] + (is * 256 + wid * 64) * 16);
    }
  };

  // prologue: queue order (oldest->newest) = K(s0), V(s0), K(s0+1)
  stageK(s0, s0 % 3);
  stageV(s0, s0 & 1);
  if (s0 + 1 < s1) stageK(s0 + 1, (s0 + 1) % 3);

  const f32x16 z16 = {};
  f32x16 oa0 = {}, oa1 = {};
  float rs = 0.0f;

  for (int kt = s0; kt < s1; ++kt) {
    const int k0 = kt * BK;
    const bool live = (k0 <= qmax);        // wave-uniform causal skip
    // ---- top gate: K(kt) landed in all waves ---------------------------
    if (kt + 1 < s1) { asm volatile("s_waitcnt vmcnt(4)" ::: "memory"); }
    else             { asm volatile("s_waitcnt vmcnt(2)" ::: "memory"); }
    __builtin_amdgcn_s_barrier();
    __builtin_amdgcn_sched_barrier(0);
    // ---- issue next stages (buffers freed by barrier above) ------------
    if (kt + 1 < s1) stageV(kt + 1, (kt + 1) & 1);
    if (kt + 2 < s1) stageK(kt + 2, (kt + 2) % 3);

    unsigned pw[16];
    if (live) {
      const bf16_t* ksb = Ks[kt % 3];
      // ---- S^T = K Q^T (swapped): sc{0,1} = k-blocks 0..31 / 32..63 ----
      f32x16 sc0, sc1;
      {
        const bf16x8 kf0 = *(const bf16x8*)&ksb[(hi * 64 + l31) * 8];
        const bf16x8 kf1 = *(const bf16x8*)&ksb[(hi * 64 + 32 + l31) * 8];
        sc0 = __builtin_amdgcn_mfma_f32_32x32x16_bf16(kf0, qf[0], z16, 0, 0, 0);
        sc1 = __builtin_amdgcn_mfma_f32_32x32x16_bf16(kf1, qf[0], z16, 0, 0, 0);
      }
#pragma unroll
      for (int ks = 1; ks < 4; ++ks) {
        const bf16x8 kf0 = *(const bf16x8*)&ksb[((ks * 2 + hi) * 64 + l31) * 8];
        const bf16x8 kf1 = *(const bf16x8*)&ksb[((ks * 2 + hi) * 64 + 32 + l31) * 8];
        sc0 = __builtin_amdgcn_mfma_f32_32x32x16_bf16(kf0, qf[ks], sc0, 0, 0, 0);
        sc1 = __builtin_amdgcn_mfma_f32_32x32x16_bf16(kf1, qf[ks], sc1, 0, 0, 0);
      }
      // ---- causal mask (value compare, compile-time reg indices) -------
      if (k0 + 63 > qmin) {
        const int qg = qmin + l31;
#pragma unroll
        for (int r = 0; r < 16; ++r) {
          const int kg = k0 + (r & 3) + 8 * (r >> 2) + 4 * hi;
          if (kg > qg)      sc0[r] = -1e30f;
          if (kg + 32 > qg) sc1[r] = -1e30f;
        }
      }
      // ---- P = exp2(S) in place ----------------------------------------
#pragma unroll
      for (int r = 0; r < 16; ++r) {
        sc0[r] = __builtin_amdgcn_exp2f(sc0[r]);
        sc1[r] = __builtin_amdgcn_exp2f(sc1[r]);
      }
      // ---- rowsum (this lane's k-half of column q = qmin+l31) ----------
      {
        float s0a = 0.f, s1a = 0.f, s2a = 0.f, s3a = 0.f;
#pragma unroll
        for (int r = 0; r < 16; r += 4) {
          s0a += sc0[r]     + sc1[r];
          s1a += sc0[r + 1] + sc1[r + 1];
          s2a += sc0[r + 2] + sc1[r + 2];
          s3a += sc0[r + 3] + sc1[r + 3];
        }
        rs += (s0a + s1a) + (s2a + s3a);
      }
      // ---- pack P -> PV A-fragments (cvt_pk + permlane32_swap) ---------
      {
        unsigned a0 = pk_bf16(sc0[0], sc0[1]),   a1 = pk_bf16(sc0[2], sc0[3]);
        unsigned b0 = pk_bf16(sc0[4], sc0[5]),   b1 = pk_bf16(sc0[6], sc0[7]);
        unsigned c0 = pk_bf16(sc0[8], sc0[9]),   c1 = pk_bf16(sc0[10], sc0[11]);
        unsigned d0 = pk_bf16(sc0[12], sc0[13]), d1 = pk_bf16(sc0[14], sc0[15]);
        asm("v_permlane32_swap_b32 %0, %1" : "+v"(a0), "+v"(b0));
        asm("v_permlane32_swap_b32 %0, %1" : "+v"(a1), "+v"(b1));
        asm("v_permlane32_swap_b32 %0, %1" : "+v"(c0), "+v"(d0));
        asm("v_permlane32_swap_b32 %0, %1" : "+v"(c1), "+v"(d1));
        pw[0] = a0; pw[1] = a1; pw[2] = b0; pw[3] = b1;
        pw[4] = c0; pw[5] = c1; pw[6] = d0; pw[7] = d1;
      }
      {
        unsigned a0 = pk_bf16(sc1[0], sc1[1]),   a1 = pk_bf16(sc1[2], sc1[3]);
        unsigned b0 = pk_bf16(sc1[4], sc1[5]),   b1 = pk_bf16(sc1[6], sc1[7]);
        unsigned c0 = pk_bf16(sc1[8], sc1[9]),   c1 = pk_bf16(sc1[10], sc1[11]);
        unsigned d0 = pk_bf16(sc1[12], sc1[13]), d1 = pk_bf16(sc1[14], sc1[15]);
        asm("v_permlane32_swap_b32 %0, %1" : "+v"(a0), "+v"(b0));
        asm("v_permlane32_swap_b32 %0, %1" : "+v"(a1), "+v"(b1));
        asm("v_permlane32_swap_b32 %0, %1" : "+v"(c0), "+v"(d0));
        asm("v_permlane32_swap_b32 %0, %1" : "+v"(c1), "+v"(d1));
        pw[8]  = a0; pw[9]  = a1; pw[10] = b0; pw[11] = b1;
        pw[12] = c0; pw[13] = c1; pw[14] = d0; pw[15] = d1;
      }
    }
    // ---- mid gate: V(kt) landed in all waves (uniform, outside `live`) --
    if (kt + 2 < s1)      { asm volatile("s_waitcnt vmcnt(6)" ::: "memory"); }
    else if (kt + 1 < s1) { asm volatile("s_waitcnt vmcnt(4)" ::: "memory"); }
    else                  { asm volatile("s_waitcnt vmcnt(0)" ::: "memory"); }
    __builtin_amdgcn_s_barrier();
    __builtin_amdgcn_sched_barrier(0);
    if (live) {
      const bf16_t* vsb = Vs[kt & 1];
      // ---- O += P V ----------------------------------------------------
      union U8 { unsigned u[4]; bf16x8 v; };
#pragma unroll
      for (int kb = 0; kb < 2; ++kb)
#pragma unroll
        for (int ks2 = 0; ks2 < 2; ++ks2) {
          U8 pu;
          pu.u[0] = pw[kb * 8 + ks2 * 4 + 0];
          pu.u[1] = pw[kb * 8 + ks2 * 4 + 1];
          pu.u[2] = pw[kb * 8 + ks2 * 4 + 2];
          pu.u[3] = pw[kb * 8 + ks2 * 4 + 3];
          const int pnl = kb * 4 + ks2 * 2 + hi;
          const bf16x8 vf0 = *(const bf16x8*)&vsb[(pnl * 64 + l31) * 8];
          const bf16x8 vf1 = *(const bf16x8*)&vsb[(pnl * 64 + 32 + l31) * 8];
          oa0 = __builtin_amdgcn_mfma_f32_32x32x16_bf16(pu.v, vf0, oa0, 0, 0, 0);
          oa1 = __builtin_amdgcn_mfma_f32_32x32x16_bf16(pu.v, vf1, oa1, 0, 0, 0);
        }
    }
  }

  // ---- epilogue ----------------------------------------------------------
  const float full = rs + __shfl(rs, lane ^ 32);
  if (direct) {
    __syncthreads();                       // all waves out of main loop
    if (lane < 32) rsbuf[wid * 32 + l31] = full;
    __syncthreads();
#pragma unroll
    for (int r = 0; r < 16; ++r) {
      const int crow = (r & 3) + 8 * (r >> 2) + 4 * hi;
      const float inv = __builtin_amdgcn_rcpf(rsbuf[wid * 32 + crow]);
      const int row = q0 + wid * 32 + crow;
      const size_t rowoff = ((size_t)(b * S + row)) * E + h * D;
      O[rowoff + l31]      = (bf16_t)(oa0[r] * inv);
      O[rowoff + 32 + l31] = (bf16_t)(oa1[r] * inv);
    }
  } else {
    // plain-store partials (rows 1024..2047), buffer selected by k-half
    float* Oh = Oacc + (size_t)half * (64 * 1024 * 64);
    float* Rh = Racc + (size_t)half * (64 * 1024);
    if (lane < 32) Rh[(size_t)bh * 1024 + (qmin + l31 - 1024)] = full;
#pragma unroll
    for (int r = 0; r < 16; ++r) {
      const int crow = (r & 3) + 8 * (r >> 2) + 4 * hi;
      const int row = q0 + wid * 32 + crow;
      float* dst = &Oh[((size_t)bh * 1024 + (row - 1024)) * 64];
      dst[l31]      = oa0[r];
      dst[32 + l31] = oa1[r];
    }
  }
}

// ---------------------------------------------------------------------------
// Combine + normalize split-k partials: rows 1024..2047 of each (b,h).
// ---------------------------------------------------------------------------
__global__ void attn_norm_kernel(const float* __restrict__ Oacc,
                                 const float* __restrict__ Racc,
                                 bf16_t* __restrict__ O) {
  constexpr size_t OHALF = (size_t)64 * 1024 * 64;
  constexpr size_t RHALF = (size_t)64 * 1024;
  const int g = blockIdx.x * 256 + threadIdx.x;   // [0, 64*1024*16)
  const int r = g >> 4;                           // packed row idx [0, 65536)
  const int dq = (g & 15) * 4;
  const int bh = r >> 10, srow = r & 1023;
  const int b = bh >> 4, h = bh & 15;
  const float4 v0 = *(const float4*)&Oacc[(size_t)r * 64 + dq];
  const float4 v1 = *(const float4*)&Oacc[OHALF + (size_t)r * 64 + dq];
  const float inv = __builtin_amdgcn_rcpf(Racc[r] + Racc[RHALF + r]);
  union { bf16_t hh[4]; uint2 u; } cv;
  cv.hh[0] = (bf16_t)((v0.x + v1.x) * inv);
  cv.hh[1] = (bf16_t)((v0.y + v1.y) * inv);
  cv.hh[2] = (bf16_t)((v0.z + v1.z) * inv);
  cv.hh[3] = (bf16_t)((v0.w + v1.w) * inv);
  const size_t off = ((size_t)(b * 2048 + 1024 + srow)) * 1024 + h * 64 + dq;
  *(uint2*)&O[off] = cv.u;
}

// ---------------------------------------------------------------------------
extern "C" void kernel_launch(void* const* d_in, const int* in_sizes, int n_in,
                              void* d_out, int out_size, void* d_ws, size_t ws_size,
                              hipStream_t stream) {
  // setup_inputs order: k, v, q, Wk, Wv, Wq, Wo  (all fp32)
  const float* k_in = (const float*)d_in[0];
  const float* v_in = (const float*)d_in[1];
  const float* q_in = (const float*)d_in[2];
  const float* Wk_in = (const float*)d_in[3];
  const float* Wv_in = (const float*)d_in[4];
  const float* Wq_in = (const float*)d_in[5];
  const float* Wo_in = (const float*)d_in[6];
  float* out = (float*)d_out;

  constexpr int    M = 8192, N = 1024, K = 1024;
  constexpr size_t SZ_X = (size_t)M * K * 2;
  constexpr size_t SZ_W = (size_t)N * K * 2;

  char* ws = (char*)d_ws;
  bf16_t* qb  = (bf16_t*)(ws);
  bf16_t* kb  = (bf16_t*)(ws + SZ_X);
  bf16_t* vb  = (bf16_t*)(ws + 2 * SZ_X);
  bf16_t* wkb = (bf16_t*)(ws + 3 * SZ_X);
  bf16_t* wvb = (bf16_t*)(ws + 3 * SZ_X + SZ_W);
  bf16_t* wqb = (bf16_t*)(ws + 3 * SZ_X + 2 * SZ_W);
  bf16_t* wob = (bf16_t*)(ws + 3 * SZ_X + 3 * SZ_W);
  bf16_t* Qp  = (bf16_t*)(ws + 3 * SZ_X + 4 * SZ_W);
  bf16_t* Kp  = (bf16_t*)(ws + 4 * SZ_X + 4 * SZ_W);
  bf16_t* Vtg = (bf16_t*)(ws + 5 * SZ_X + 4 * SZ_W);
  bf16_t* Ob  = qb;    // qb dead after Q projection
  // kb/vb dead after qkv: 2x16MB fp32 O-partials (plain stores, no init).
  // wkb/wvb dead after qkv: 2x256KB fp32 rowsum partials.
  float* Oacc = (float*)(ws + SZ_X);            // [2][64*1024*64] f32
  float* Racc = (float*)(ws + 3 * SZ_X);        // [2][64*1024] f32

  cvt_all_kernel<<<28672, 256, 0, stream>>>(q_in, k_in, v_in, Wk_in, Wv_in, Wq_in, Wo_in,
                                            (uint2*)ws);

  // Q scale = (1/sqrt(D)) * log2(e): scores in log2 domain for exp2 softmax
  qkv_kernel<<<dim3(1536), 256, 0, stream>>>(qb, kb, vb, wqb, wkb, wvb,
                                             Qp, Kp, Vtg, 0.125f * 1.44269504f);

  attn_kernel<<<dim3(1536), 256, 0, stream>>>(Qp, Kp, Vtg, Ob, Oacc, Racc);

  attn_norm_kernel<<<4096, 256, 0, stream>>>(Oacc, Racc, Ob);

  out_gemm_kernel<<<dim3(512), 256, 0, stream>>>(Ob, wob, out, M, N, K);
}